// Round 4
// baseline (246.640 us; speedup 1.0000x reference)
//
#include <hip/hip_runtime.h>
#include <hip/hip_bf16.h>
#include <math.h>

constexpr int CH = 256;       // input channels
constexpr int CC = 512;       // concat width
constexpr int AP = 16;        // padded alpha row stride (12 heads used)

typedef __bf16 bf16x8 __attribute__((ext_vector_type(8)));
typedef float  f32x4  __attribute__((ext_vector_type(4)));
typedef __attribute__((address_space(3))) void lds_void;
typedef __attribute__((address_space(1))) void glb_void;

__device__ inline unsigned short f2bf(float f) {
    union { float f; unsigned u; } v; v.f = f;
    unsigned r = v.u + 0x7FFFu + ((v.u >> 16) & 1u);
    return (unsigned short)(r >> 16);
}
__device__ inline float bfbits(unsigned lo16) {
    union { unsigned u; float f; } v; v.u = lo16 << 16;
    return v.f;
}

// ---------------------------------------------------------------------------
// Fused pre-pass: LN(->bf16) + weight transpose/convert + deg init
// blocks [0,LNB): LN ; [LNB,LNB+512): WT1 ; [LNB+512,LNB+1024): WTu ; rest: deg
// ---------------------------------------------------------------------------
__global__ void fused_pre_kernel(const float* __restrict__ x, const float* __restrict__ gamma,
                                 const float* __restrict__ beta,
                                 const float* __restrict__ W1, const float* __restrict__ W2,
                                 const float* __restrict__ Wu,
                                 unsigned short* __restrict__ xnb,
                                 unsigned short* __restrict__ WT1, unsigned short* __restrict__ WTu,
                                 int* __restrict__ deg, int N, int LNB) {
    int b = blockIdx.x;
    int t = threadIdx.x;
    if (b < LNB) {
        int wid = b * 4 + (t >> 6);
        int lane = t & 63;
        if (wid >= N) return;
        const float4 v = *(const float4*)(x + (size_t)wid * CH + lane * 4);
        float s = v.x + v.y + v.z + v.w;
        float sq = v.x * v.x + v.y * v.y + v.z * v.z + v.w * v.w;
        #pragma unroll
        for (int o = 32; o; o >>= 1) { s += __shfl_xor(s, o); sq += __shfl_xor(sq, o); }
        float mu = s * (1.0f / CH);
        float var = sq * (1.0f / CH) - mu * mu;
        float rs = rsqrtf(var + 1e-5f);
        float4 g = *(const float4*)(gamma + lane * 4);
        float4 bb = *(const float4*)(beta + lane * 4);
        unsigned short o0 = f2bf((v.x - mu) * rs * g.x + bb.x);
        unsigned short o1 = f2bf((v.y - mu) * rs * g.y + bb.y);
        unsigned short o2 = f2bf((v.z - mu) * rs * g.z + bb.z);
        unsigned short o3 = f2bf((v.w - mu) * rs * g.w + bb.w);
        uint2 pk;
        pk.x = (unsigned)o0 | ((unsigned)o1 << 16);
        pk.y = (unsigned)o2 | ((unsigned)o3 << 16);
        *(uint2*)(xnb + (size_t)wid * CH + lane * 4) = pk;
    } else if (b < LNB + 512) {
        int idx = (b - LNB) * 256 + t;              // 512*256
        int n = idx >> 8, k = idx & 255;
        float v = (n < 256) ? W1[(size_t)k * 256 + n] : W2[(size_t)k * 256 + (n - 256)];
        WT1[idx] = f2bf(v);
    } else if (b < LNB + 1024) {
        int idx = (b - LNB - 512) * 256 + t;        // 256*512
        int n = idx >> 9, k = idx & 511;
        WTu[idx] = f2bf(Wu[(size_t)k * 256 + n]);
    } else {
        int i = (b - LNB - 1024) * 256 + t;
        if (i < N) deg[i] = 1;                      // self-loop
    }
}

// ---------------------------------------------------------------------------
// bf16 MFMA GEMM core, 128x128 tile, BK=64, 4 waves (each 64x64 out)
// LDS XOR-swizzle via inverse-swizzled global source (global_load_lds linear).
// ---------------------------------------------------------------------------
__device__ inline void gemm_core(const unsigned short* __restrict__ Ab,
                                 const unsigned short* __restrict__ Bt,
                                 unsigned short* As, unsigned short* Bs,
                                 f32x4 acc[4][4], int m0, int n0, int M, int K) {
    const int t = threadIdx.x;
    const int lane = t & 63;
    const int wave = t >> 6;
    const int wr = wave >> 1, wc = wave & 1;
    const int srow = lane >> 3;                        // 0..7
    const int scol = (((lane & 7) ^ srow) << 3);       // inverse-swizzled elem col
    const int fr = lane & 15;
    const int fkb = (lane >> 4) << 4;                  // logical colbyte per 16-lane group

    for (int k0 = 0; k0 < K; k0 += 64) {
        __syncthreads();
        #pragma unroll
        for (int c = 0; c < 4; ++c) {
            int chunk = c * 4 + wave;                  // 0..15 -> 8 rows each
            int row = chunk * 8 + srow;                // 0..127
            int gra = m0 + row; if (gra >= M) gra = M - 1;
            const unsigned short* ga = Ab + (size_t)gra * K + k0 + scol;
            __builtin_amdgcn_global_load_lds((const glb_void*)ga,
                                             (lds_void*)&As[chunk * 512], 16, 0, 0);
            const unsigned short* gb = Bt + (size_t)(n0 + row) * K + k0 + scol;
            __builtin_amdgcn_global_load_lds((const glb_void*)gb,
                                             (lds_void*)&Bs[chunk * 512], 16, 0, 0);
        }
        __syncthreads();
        #pragma unroll
        for (int ks = 0; ks < 2; ++ks) {
            bf16x8 af[4], bfr[4];
            #pragma unroll
            for (int m = 0; m < 4; ++m) {
                int r = wr * 64 + m * 16 + fr;
                int cb = (ks * 64 + fkb) ^ ((r & 7) << 4);
                af[m] = *(const bf16x8*)((const char*)As + r * 128 + cb);
            }
            #pragma unroll
            for (int n = 0; n < 4; ++n) {
                int r = wc * 64 + n * 16 + fr;
                int cb = (ks * 64 + fkb) ^ ((r & 7) << 4);
                bfr[n] = *(const bf16x8*)((const char*)Bs + r * 128 + cb);
            }
            #pragma unroll
            for (int m = 0; m < 4; ++m)
                #pragma unroll
                for (int n = 0; n < 4; ++n)
                    acc[m][n] = __builtin_amdgcn_mfma_f32_16x16x32_bf16(af[m], bfr[n], acc[m][n], 0, 0, 0);
        }
    }
}

// GEMM1: h(bf16)[M,512] = xnorm @ WT1^T, fused alpha_src/dst epilogue.
// Grid swizzle co-locates same-m blocks (shared A panel) on one XCD.
__global__ __launch_bounds__(256) void gemm1_mfma(
    const unsigned short* __restrict__ Ab, const unsigned short* __restrict__ Bt,
    const float* __restrict__ as1, const float* __restrict__ ad1,
    const float* __restrict__ as2, const float* __restrict__ ad2,
    unsigned short* __restrict__ H,
    float* __restrict__ alpha_src, float* __restrict__ alpha_dst, int M, int MB) {
    __shared__ unsigned short As[128 * 64];
    __shared__ unsigned short Bs[128 * 64];
    const int s = blockIdx.x;
    const int xcd = s & 7;
    const int jj = s >> 3;
    const int n_blk = jj & 3;                          // NB=4
    const int m_blk = (jj >> 2) * 8 + xcd;
    if (m_blk >= MB) return;
    const int m0 = m_blk * 128, n0 = n_blk * 128;
    const int lane = threadIdx.x & 63;
    const int wave = threadIdx.x >> 6;
    const int wr = wave >> 1, wc = wave & 1;
    f32x4 acc[4][4] = {};
    gemm_core(Ab, Bt, As, Bs, acc, m0, n0, M, 256);
    const int fr = lane & 15;
    const int orow = (lane >> 4) * 4;
    // H store
    #pragma unroll
    for (int m = 0; m < 4; ++m)
        #pragma unroll
        for (int j = 0; j < 4; ++j) {
            int r = m0 + wr * 64 + m * 16 + orow + j;
            if (r < M) {
                #pragma unroll
                for (int n = 0; n < 4; ++n) {
                    int ccol = n0 + wc * 64 + n * 16 + fr;
                    H[(size_t)r * CC + ccol] = f2bf(acc[m][n][j]);
                }
            }
        }
    // alpha epilogue: each wave tile (64 cols) contains whole heads
    const int colbase = n0 + wc * 64;
    const bool gat1 = colbase < 256;
    float sv[4], dv[4];
    int headA;
    if (gat1) {
        headA = colbase >> 6;
        #pragma unroll
        for (int n = 0; n < 4; ++n) { int c = colbase + n * 16 + fr; sv[n] = as1[c]; dv[n] = ad1[c]; }
    } else {
        headA = 4 + ((colbase - 256) >> 5);
        #pragma unroll
        for (int n = 0; n < 4; ++n) { int c = colbase - 256 + n * 16 + fr; sv[n] = as2[c]; dv[n] = ad2[c]; }
    }
    #pragma unroll
    for (int m = 0; m < 4; ++m)
        #pragma unroll
        for (int j = 0; j < 4; ++j) {
            int r = m0 + wr * 64 + m * 16 + orow + j;
            float p01s = acc[m][0][j] * sv[0] + acc[m][1][j] * sv[1];
            float p23s = acc[m][2][j] * sv[2] + acc[m][3][j] * sv[3];
            float p01d = acc[m][0][j] * dv[0] + acc[m][1][j] * dv[1];
            float p23d = acc[m][2][j] * dv[2] + acc[m][3][j] * dv[3];
            if (gat1) {
                float ts = p01s + p23s, td = p01d + p23d;
                #pragma unroll
                for (int o = 1; o < 16; o <<= 1) { ts += __shfl_xor(ts, o); td += __shfl_xor(td, o); }
                if (fr == 0 && r < M) {
                    alpha_src[(size_t)r * AP + headA] = ts;
                    alpha_dst[(size_t)r * AP + headA] = td;
                }
            } else {
                #pragma unroll
                for (int o = 1; o < 16; o <<= 1) {
                    p01s += __shfl_xor(p01s, o); p23s += __shfl_xor(p23s, o);
                    p01d += __shfl_xor(p01d, o); p23d += __shfl_xor(p23d, o);
                }
                if (fr == 0 && r < M) {
                    alpha_src[(size_t)r * AP + headA]     = p01s;
                    alpha_dst[(size_t)r * AP + headA]     = p01d;
                    alpha_src[(size_t)r * AP + headA + 1] = p23s;
                    alpha_dst[(size_t)r * AP + headA + 1] = p23d;
                }
            }
        }
}

// GEMM2: out(f32)[M,256] = x + xcat(bf16) @ WTu^T + bu, same XCD co-location (NB=2)
__global__ __launch_bounds__(256) void gemm2_mfma(const unsigned short* __restrict__ Ab,
                                                  const unsigned short* __restrict__ Bt,
                                                  const float* __restrict__ bu,
                                                  const float* __restrict__ xres,
                                                  float* __restrict__ C, int M, int MB) {
    __shared__ unsigned short As[128 * 64];
    __shared__ unsigned short Bs[128 * 64];
    const int s = blockIdx.x;
    const int xcd = s & 7;
    const int jj = s >> 3;
    const int n_blk = jj & 1;                          // NB=2
    const int m_blk = (jj >> 1) * 8 + xcd;
    if (m_blk >= MB) return;
    const int m0 = m_blk * 128, n0 = n_blk * 128;
    const int lane = threadIdx.x & 63;
    const int wave = threadIdx.x >> 6;
    const int wr = wave >> 1, wc = wave & 1;
    f32x4 acc[4][4] = {};
    gemm_core(Ab, Bt, As, Bs, acc, m0, n0, M, 512);
    const int fr = lane & 15;
    const int orow = (lane >> 4) * 4;
    #pragma unroll
    for (int m = 0; m < 4; ++m)
        #pragma unroll
        for (int j = 0; j < 4; ++j) {
            int r = m0 + wr * 64 + m * 16 + orow + j;
            if (r < M) {
                #pragma unroll
                for (int n = 0; n < 4; ++n) {
                    int ccol = n0 + wc * 64 + n * 16 + fr;
                    C[(size_t)r * CH + ccol] = acc[m][n][j] + bu[ccol] + xres[(size_t)r * CH + ccol];
                }
            }
        }
}

// ---------------------------------------------------------------------------
// CSR build
// ---------------------------------------------------------------------------
__global__ void hist_kernel(const int* __restrict__ dst, int* __restrict__ deg, int E) {
    int i = blockIdx.x * blockDim.x + threadIdx.x;
    if (i < E) atomicAdd(&deg[dst[i]], 1);
}
__global__ __launch_bounds__(256) void scan1_kernel(const int* __restrict__ deg, int* __restrict__ pre,
                                                    int* __restrict__ bsum, int n) {
    __shared__ int wsum[4];
    int t = threadIdx.x, lane = t & 63, w = t >> 6;
    int base = blockIdx.x * 1024 + t * 4;
    int v0 = base     < n ? deg[base]     : 0;
    int v1 = base + 1 < n ? deg[base + 1] : 0;
    int v2 = base + 2 < n ? deg[base + 2] : 0;
    int v3 = base + 3 < n ? deg[base + 3] : 0;
    int s = v0 + v1 + v2 + v3;
    int sc = s;
    #pragma unroll
    for (int o = 1; o < 64; o <<= 1) { int xx = __shfl_up(sc, o); if (lane >= o) sc += xx; }
    if (lane == 63) wsum[w] = sc;
    __syncthreads();
    int wo = 0;
    #pragma unroll
    for (int k = 0; k < 4; ++k) if (k < w) wo += wsum[k];
    int p = wo + sc - s;
    if (base     < n) pre[base]     = p; p += v0;
    if (base + 1 < n) pre[base + 1] = p; p += v1;
    if (base + 2 < n) pre[base + 2] = p; p += v2;
    if (base + 3 < n) pre[base + 3] = p;
    if (t == 255) bsum[blockIdx.x] = wo + sc;
}
__global__ void scan2_kernel(int* __restrict__ bsum, int nb) {
    int lane = threadIdx.x;
    int v = lane < nb ? bsum[lane] : 0;
    int sc = v;
    #pragma unroll
    for (int o = 1; o < 64; o <<= 1) { int xx = __shfl_up(sc, o); if (lane >= o) sc += xx; }
    if (lane < nb) bsum[lane] = sc - v;
}
// scan3 + csr_init fused: finalize offsets, seed cursor & self-loop
__global__ void scan3_csr_kernel(const int* __restrict__ pre, const int* __restrict__ bsum,
                                 int* __restrict__ offsets, int* __restrict__ cursor,
                                 int* __restrict__ csr, int n, int total) {
    int i = blockIdx.x * 256 + threadIdx.x;
    if (i < n) {
        int off = pre[i] + bsum[i >> 10];
        offsets[i] = off;
        cursor[i] = off + 1;
        csr[off] = i;                                  // self-loop slot 0
    }
    if (i == 0) offsets[n] = total;
}
__global__ void scatter_kernel(const int* __restrict__ src, const int* __restrict__ dst,
                               int* __restrict__ cursor, int* __restrict__ csr, int E) {
    int i = blockIdx.x * blockDim.x + threadIdx.x;
    if (i < E) {
        int pos = atomicAdd(&cursor[dst[i]], 1);
        csr[pos] = src[i];
    }
}

// ---------------------------------------------------------------------------
// Aggregation: single edge pass, post-normalized softmax, 4x unrolled.
// ---------------------------------------------------------------------------
__global__ void aggregate_kernel(const unsigned short* __restrict__ Hb,
                                 const float* __restrict__ alpha_src,
                                 const float* __restrict__ alpha_dst,
                                 const int* __restrict__ offsets,
                                 const int* __restrict__ csr,
                                 const float* __restrict__ b1, const float* __restrict__ b2,
                                 unsigned short* __restrict__ xcb, int N) {
    int n = (blockIdx.x * blockDim.x + threadIdx.x) >> 6;
    int lane = threadIdx.x & 63;
    if (n >= N) return;
    int beg = offsets[n], end = offsets[n + 1];
    int c0 = lane * 8;
    int hid = (lane < 32) ? (lane >> 3) : (4 + ((lane - 32) >> 2));
    float adh = alpha_dst[(size_t)n * AP + hid];

    float ssum = 0.f;
    float a0 = 0, a1 = 0, a2 = 0, a3 = 0, a4 = 0, a5 = 0, a6 = 0, a7 = 0;

    int i = beg;
    for (; i + 4 <= end; i += 4) {
        int ss[4];
        #pragma unroll
        for (int u = 0; u < 4; ++u) ss[u] = csr[i + u];
        float lw[4];
        #pragma unroll
        for (int u = 0; u < 4; ++u) lw[u] = alpha_src[(size_t)ss[u] * AP + hid];
        int4 hv[4];
        #pragma unroll
        for (int u = 0; u < 4; ++u) hv[u] = *(const int4*)(Hb + (size_t)ss[u] * CC + c0);
        #pragma unroll
        for (int u = 0; u < 4; ++u) {
            float l = lw[u] + adh;
            l = l > 0.f ? l : 0.2f * l;
            float wv = __expf(l);
            ssum += wv;
            a0 += wv * bfbits((unsigned)hv[u].x & 0xffffu);
            a1 += wv * bfbits((unsigned)hv[u].x >> 16);
            a2 += wv * bfbits((unsigned)hv[u].y & 0xffffu);
            a3 += wv * bfbits((unsigned)hv[u].y >> 16);
            a4 += wv * bfbits((unsigned)hv[u].z & 0xffffu);
            a5 += wv * bfbits((unsigned)hv[u].z >> 16);
            a6 += wv * bfbits((unsigned)hv[u].w & 0xffffu);
            a7 += wv * bfbits((unsigned)hv[u].w >> 16);
        }
    }
    for (; i < end; ++i) {
        int s0 = csr[i];
        float l = alpha_src[(size_t)s0 * AP + hid] + adh;
        int4 hv0 = *(const int4*)(Hb + (size_t)s0 * CC + c0);
        l = l > 0.f ? l : 0.2f * l;
        float wv = __expf(l);
        ssum += wv;
        a0 += wv * bfbits((unsigned)hv0.x & 0xffffu);
        a1 += wv * bfbits((unsigned)hv0.x >> 16);
        a2 += wv * bfbits((unsigned)hv0.y & 0xffffu);
        a3 += wv * bfbits((unsigned)hv0.y >> 16);
        a4 += wv * bfbits((unsigned)hv0.z & 0xffffu);
        a5 += wv * bfbits((unsigned)hv0.z >> 16);
        a6 += wv * bfbits((unsigned)hv0.w & 0xffffu);
        a7 += wv * bfbits((unsigned)hv0.w >> 16);
    }

    float inv = 1.0f / (ssum + 1e-16f);
    const float* bb = (c0 < 256) ? (b1 + c0) : (b2 + (c0 - 256));
    float4 bb0 = *(const float4*)(bb), bb1 = *(const float4*)(bb + 4);
    float o[8];
    o[0] = a0 * inv + bb0.x; o[1] = a1 * inv + bb0.y; o[2] = a2 * inv + bb0.z; o[3] = a3 * inv + bb0.w;
    o[4] = a4 * inv + bb1.x; o[5] = a5 * inv + bb1.y; o[6] = a6 * inv + bb1.z; o[7] = a7 * inv + bb1.w;
    #pragma unroll
    for (int j = 0; j < 8; ++j) o[j] = o[j] > 0.f ? o[j] : expm1f(o[j]);
    unsigned short u[8];
    #pragma unroll
    for (int j = 0; j < 8; ++j) u[j] = f2bf(o[j]);
    int4 pk;
    pk.x = (int)((unsigned)u[0] | ((unsigned)u[1] << 16));
    pk.y = (int)((unsigned)u[2] | ((unsigned)u[3] << 16));
    pk.z = (int)((unsigned)u[4] | ((unsigned)u[5] << 16));
    pk.w = (int)((unsigned)u[6] | ((unsigned)u[7] << 16));
    *(int4*)(xcb + (size_t)n * CC + c0) = pk;
}

// ---------------------------------------------------------------------------
// Launch
// ---------------------------------------------------------------------------
extern "C" void kernel_launch(void* const* d_in, const int* in_sizes, int n_in,
                              void* d_out, int out_size, void* d_ws, size_t ws_size,
                              hipStream_t stream) {
    const float* x     = (const float*)d_in[0];
    const int*   ei    = (const int*)d_in[1];
    const float* gamma = (const float*)d_in[2];
    const float* beta  = (const float*)d_in[3];
    const float* W1    = (const float*)d_in[4];
    const float* as1   = (const float*)d_in[5];
    const float* ad1   = (const float*)d_in[6];
    const float* b1    = (const float*)d_in[7];
    const float* W2    = (const float*)d_in[8];
    const float* as2   = (const float*)d_in[9];
    const float* ad2   = (const float*)d_in[10];
    const float* b2    = (const float*)d_in[11];
    const float* Wu    = (const float*)d_in[12];
    const float* bu    = (const float*)d_in[13];
    float* out = (float*)d_out;

    const int N = in_sizes[0] / CH;
    const int E = in_sizes[1] / 2;
    const int* src = ei;
    const int* dst = ei + E;

    char* w = (char*)d_ws;
    auto alloc = [&](size_t bytes) { char* p = w; w += (bytes + 255) & ~(size_t)255; return p; };
    unsigned short* Hb  = (unsigned short*)alloc((size_t)N * CC * 2);
    unsigned short* xnb = (unsigned short*)alloc((size_t)N * CH * 2);
    unsigned short* xcb = (unsigned short*)alloc((size_t)N * CC * 2);
    unsigned short* WT1 = (unsigned short*)alloc(512 * 256 * 2);
    unsigned short* WTu = (unsigned short*)alloc(256 * 512 * 2);
    float* alpha_src = (float*)alloc((size_t)N * AP * 4);
    float* alpha_dst = (float*)alloc((size_t)N * AP * 4);
    int* deg     = (int*)alloc((size_t)N * 4);
    int* pre     = (int*)alloc((size_t)N * 4);
    int* bsum    = (int*)alloc(64 * 4);
    int* offsets = (int*)alloc(((size_t)N + 1) * 4);
    int* cursor  = (int*)alloc((size_t)N * 4);
    int* csr     = (int*)alloc(((size_t)E + N) * 4);

    const int LNB = (N + 3) / 4;
    const int DEGB = (N + 255) / 256;
    fused_pre_kernel<<<LNB + 1024 + DEGB, 256, 0, stream>>>(x, gamma, beta, W1, W2, Wu,
                                                            xnb, WT1, WTu, deg, N, LNB);

    const int MB = (N + 127) / 128;
    const int MB8 = ((MB + 7) / 8) * 8;
    gemm1_mfma<<<MB8 * 4, 256, 0, stream>>>(xnb, WT1, as1, ad1, as2, ad2,
                                            Hb, alpha_src, alpha_dst, N, MB);

    hist_kernel<<<(E + 255) / 256, 256, 0, stream>>>(dst, deg, E);
    int nb = (N + 1023) / 1024;
    scan1_kernel<<<nb, 256, 0, stream>>>(deg, pre, bsum, N);
    scan2_kernel<<<1, 64, 0, stream>>>(bsum, nb);
    scan3_csr_kernel<<<(N + 255) / 256, 256, 0, stream>>>(pre, bsum, offsets, cursor, csr, N, E + N);
    scatter_kernel<<<(E + 255) / 256, 256, 0, stream>>>(src, dst, cursor, csr, E);

    aggregate_kernel<<<(N + 3) / 4, 256, 0, stream>>>(Hb, alpha_src, alpha_dst, offsets, csr,
                                                      b1, b2, xcb, N);

    gemm2_mfma<<<MB8 * 2, 256, 0, stream>>>(xcb, WTu, bu, x, out, N, MB);
}

// Round 6
// 220.993 us; speedup vs baseline: 1.1161x; 1.1161x over previous
//
#include <hip/hip_runtime.h>
#include <hip/hip_bf16.h>
#include <math.h>

constexpr int CH = 256;       // input channels
constexpr int CC = 512;       // concat width
constexpr int AP = 16;        // padded alpha row stride (12 heads used)

typedef __bf16 bf16x8 __attribute__((ext_vector_type(8)));
typedef float  f32x4  __attribute__((ext_vector_type(4)));
typedef float  f32x2  __attribute__((ext_vector_type(2)));
typedef int    i32x4  __attribute__((ext_vector_type(4)));
typedef __attribute__((address_space(3))) void lds_void;
typedef __attribute__((address_space(1))) void glb_void;

__device__ inline unsigned short f2bf(float f) {
    union { float f; unsigned u; } v; v.f = f;
    unsigned r = v.u + 0x7FFFu + ((v.u >> 16) & 1u);
    return (unsigned short)(r >> 16);
}

// ---------------------------------------------------------------------------
// Fused pre-pass: LN(->bf16) + weight transpose/convert + deg init
// ---------------------------------------------------------------------------
__global__ void fused_pre_kernel(const float* __restrict__ x, const float* __restrict__ gamma,
                                 const float* __restrict__ beta,
                                 const float* __restrict__ W1, const float* __restrict__ W2,
                                 const float* __restrict__ Wu,
                                 unsigned short* __restrict__ xnb,
                                 unsigned short* __restrict__ WT1, unsigned short* __restrict__ WTu,
                                 int* __restrict__ deg, int N, int LNB) {
    int b = blockIdx.x;
    int t = threadIdx.x;
    if (b < LNB) {
        int wid = b * 4 + (t >> 6);
        int lane = t & 63;
        if (wid >= N) return;
        const float4 v = *(const float4*)(x + (size_t)wid * CH + lane * 4);
        float s = v.x + v.y + v.z + v.w;
        float sq = v.x * v.x + v.y * v.y + v.z * v.z + v.w * v.w;
        #pragma unroll
        for (int o = 32; o; o >>= 1) { s += __shfl_xor(s, o); sq += __shfl_xor(sq, o); }
        float mu = s * (1.0f / CH);
        float var = sq * (1.0f / CH) - mu * mu;
        float rs = rsqrtf(var + 1e-5f);
        float4 g = *(const float4*)(gamma + lane * 4);
        float4 bb = *(const float4*)(beta + lane * 4);
        unsigned short o0 = f2bf((v.x - mu) * rs * g.x + bb.x);
        unsigned short o1 = f2bf((v.y - mu) * rs * g.y + bb.y);
        unsigned short o2 = f2bf((v.z - mu) * rs * g.z + bb.z);
        unsigned short o3 = f2bf((v.w - mu) * rs * g.w + bb.w);
        uint2 pk;
        pk.x = (unsigned)o0 | ((unsigned)o1 << 16);
        pk.y = (unsigned)o2 | ((unsigned)o3 << 16);
        *(uint2*)(xnb + (size_t)wid * CH + lane * 4) = pk;
    } else if (b < LNB + 512) {
        int idx = (b - LNB) * 256 + t;              // 512*256
        int n = idx >> 8, k = idx & 255;
        float v = (n < 256) ? W1[(size_t)k * 256 + n] : W2[(size_t)k * 256 + (n - 256)];
        WT1[idx] = f2bf(v);
    } else if (b < LNB + 1024) {
        int idx = (b - LNB - 512) * 256 + t;        // 256*512
        int n = idx >> 9, k = idx & 511;
        WTu[idx] = f2bf(Wu[(size_t)k * 256 + n]);
    } else {
        int i = (b - LNB - 1024) * 256 + t;
        if (i < N) deg[i] = 1;                      // self-loop
    }
}

// ---------------------------------------------------------------------------
// bf16 MFMA GEMM core, 128x128 tile, BK=64, 4 waves (each 64x64 out)
// LDS XOR-swizzle via inverse-swizzled global source (global_load_lds linear).
// ---------------------------------------------------------------------------
__device__ inline void gemm_core(const unsigned short* __restrict__ Ab,
                                 const unsigned short* __restrict__ Bt,
                                 unsigned short* As, unsigned short* Bs,
                                 f32x4 acc[4][4], int m0, int n0, int M, int K) {
    const int t = threadIdx.x;
    const int lane = t & 63;
    const int wave = t >> 6;
    const int wr = wave >> 1, wc = wave & 1;
    const int srow = lane >> 3;                        // 0..7
    const int scol = (((lane & 7) ^ srow) << 3);       // inverse-swizzled elem col
    const int fr = lane & 15;
    const int fkb = (lane >> 4) << 4;                  // logical colbyte per 16-lane group

    for (int k0 = 0; k0 < K; k0 += 64) {
        __syncthreads();
        #pragma unroll
        for (int c = 0; c < 4; ++c) {
            int chunk = c * 4 + wave;                  // 0..15 -> 8 rows each
            int row = chunk * 8 + srow;                // 0..127
            int gra = m0 + row; if (gra >= M) gra = M - 1;
            const unsigned short* ga = Ab + (size_t)gra * K + k0 + scol;
            __builtin_amdgcn_global_load_lds((const glb_void*)ga,
                                             (lds_void*)&As[chunk * 512], 16, 0, 0);
            const unsigned short* gb = Bt + (size_t)(n0 + row) * K + k0 + scol;
            __builtin_amdgcn_global_load_lds((const glb_void*)gb,
                                             (lds_void*)&Bs[chunk * 512], 16, 0, 0);
        }
        __syncthreads();
        #pragma unroll
        for (int ks = 0; ks < 2; ++ks) {
            bf16x8 af[4], bfr[4];
            #pragma unroll
            for (int m = 0; m < 4; ++m) {
                int r = wr * 64 + m * 16 + fr;
                int cb = (ks * 64 + fkb) ^ ((r & 7) << 4);
                af[m] = *(const bf16x8*)((const char*)As + r * 128 + cb);
            }
            #pragma unroll
            for (int n = 0; n < 4; ++n) {
                int r = wc * 64 + n * 16 + fr;
                int cb = (ks * 64 + fkb) ^ ((r & 7) << 4);
                bfr[n] = *(const bf16x8*)((const char*)Bs + r * 128 + cb);
            }
            #pragma unroll
            for (int m = 0; m < 4; ++m)
                #pragma unroll
                for (int n = 0; n < 4; ++n)
                    acc[m][n] = __builtin_amdgcn_mfma_f32_16x16x32_bf16(af[m], bfr[n], acc[m][n], 0, 0, 0);
        }
    }
}

// GEMM1: h(fp8 e4m3)[M,512] = xnorm @ WT1^T, fused alpha_src/dst epilogue.
__global__ __launch_bounds__(256) void gemm1_mfma(
    const unsigned short* __restrict__ Ab, const unsigned short* __restrict__ Bt,
    const float* __restrict__ as1, const float* __restrict__ ad1,
    const float* __restrict__ as2, const float* __restrict__ ad2,
    unsigned char* __restrict__ Hq,
    float* __restrict__ alpha_src, float* __restrict__ alpha_dst, int M, int MB) {
    __shared__ unsigned short As[128 * 64];
    __shared__ unsigned short Bs[128 * 64];
    const int s = blockIdx.x;
    const int xcd = s & 7;
    const int jj = s >> 3;
    const int n_blk = jj & 3;                          // NB=4
    const int m_blk = (jj >> 2) * 8 + xcd;
    if (m_blk >= MB) return;
    const int m0 = m_blk * 128, n0 = n_blk * 128;
    const int lane = threadIdx.x & 63;
    const int wave = threadIdx.x >> 6;
    const int wr = wave >> 1, wc = wave & 1;
    f32x4 acc[4][4] = {};
    gemm_core(Ab, Bt, As, Bs, acc, m0, n0, M, 256);
    const int fr = lane & 15;
    const int orow = (lane >> 4) * 4;
    // H store as fp8 e4m3 (HW cvt, per-value byte store)
    #pragma unroll
    for (int m = 0; m < 4; ++m)
        #pragma unroll
        for (int j = 0; j < 4; ++j) {
            int r = m0 + wr * 64 + m * 16 + orow + j;
            if (r < M) {
                #pragma unroll
                for (int n = 0; n < 4; ++n) {
                    int ccol = n0 + wc * 64 + n * 16 + fr;
                    unsigned q = (unsigned)__builtin_amdgcn_cvt_pk_fp8_f32(
                        acc[m][n][j], acc[m][n][j], 0, false) & 0xffu;
                    Hq[(size_t)r * CC + ccol] = (unsigned char)q;
                }
            }
        }
    // alpha epilogue: each wave tile (64 cols) contains whole heads
    const int colbase = n0 + wc * 64;
    const bool gat1 = colbase < 256;
    float sv[4], dv[4];
    int headA;
    if (gat1) {
        headA = colbase >> 6;
        #pragma unroll
        for (int n = 0; n < 4; ++n) { int c = colbase + n * 16 + fr; sv[n] = as1[c]; dv[n] = ad1[c]; }
    } else {
        headA = 4 + ((colbase - 256) >> 5);
        #pragma unroll
        for (int n = 0; n < 4; ++n) { int c = colbase - 256 + n * 16 + fr; sv[n] = as2[c]; dv[n] = ad2[c]; }
    }
    #pragma unroll
    for (int m = 0; m < 4; ++m)
        #pragma unroll
        for (int j = 0; j < 4; ++j) {
            int r = m0 + wr * 64 + m * 16 + orow + j;
            float p01s = acc[m][0][j] * sv[0] + acc[m][1][j] * sv[1];
            float p23s = acc[m][2][j] * sv[2] + acc[m][3][j] * sv[3];
            float p01d = acc[m][0][j] * dv[0] + acc[m][1][j] * dv[1];
            float p23d = acc[m][2][j] * dv[2] + acc[m][3][j] * dv[3];
            if (gat1) {
                float ts = p01s + p23s, td = p01d + p23d;
                #pragma unroll
                for (int o = 1; o < 16; o <<= 1) { ts += __shfl_xor(ts, o); td += __shfl_xor(td, o); }
                if (fr == 0 && r < M) {
                    alpha_src[(size_t)r * AP + headA] = ts;
                    alpha_dst[(size_t)r * AP + headA] = td;
                }
            } else {
                #pragma unroll
                for (int o = 1; o < 16; o <<= 1) {
                    p01s += __shfl_xor(p01s, o); p23s += __shfl_xor(p23s, o);
                    p01d += __shfl_xor(p01d, o); p23d += __shfl_xor(p23d, o);
                }
                if (fr == 0 && r < M) {
                    alpha_src[(size_t)r * AP + headA]     = p01s;
                    alpha_dst[(size_t)r * AP + headA]     = p01d;
                    alpha_src[(size_t)r * AP + headA + 1] = p23s;
                    alpha_dst[(size_t)r * AP + headA + 1] = p23d;
                }
            }
        }
}

// GEMM2: out(f32)[M,256] = x + xcat(bf16) @ WTu^T + bu  (nt residual/out)
__global__ __launch_bounds__(256) void gemm2_mfma(const unsigned short* __restrict__ Ab,
                                                  const unsigned short* __restrict__ Bt,
                                                  const float* __restrict__ bu,
                                                  const float* __restrict__ xres,
                                                  float* __restrict__ C, int M, int MB) {
    __shared__ unsigned short As[128 * 64];
    __shared__ unsigned short Bs[128 * 64];
    const int s = blockIdx.x;
    const int xcd = s & 7;
    const int jj = s >> 3;
    const int n_blk = jj & 1;                          // NB=2
    const int m_blk = (jj >> 1) * 8 + xcd;
    if (m_blk >= MB) return;
    const int m0 = m_blk * 128, n0 = n_blk * 128;
    const int lane = threadIdx.x & 63;
    const int wave = threadIdx.x >> 6;
    const int wr = wave >> 1, wc = wave & 1;
    f32x4 acc[4][4] = {};
    gemm_core(Ab, Bt, As, Bs, acc, m0, n0, M, 512);
    const int fr = lane & 15;
    const int orow = (lane >> 4) * 4;
    #pragma unroll
    for (int m = 0; m < 4; ++m)
        #pragma unroll
        for (int j = 0; j < 4; ++j) {
            int r = m0 + wr * 64 + m * 16 + orow + j;
            if (r < M) {
                #pragma unroll
                for (int n = 0; n < 4; ++n) {
                    int ccol = n0 + wc * 64 + n * 16 + fr;
                    float xr = __builtin_nontemporal_load(&xres[(size_t)r * CH + ccol]);
                    __builtin_nontemporal_store(acc[m][n][j] + bu[ccol] + xr,
                                                &C[(size_t)r * CH + ccol]);
                }
            }
        }
}

// ---------------------------------------------------------------------------
// CSR build
// ---------------------------------------------------------------------------
__global__ void hist_kernel(const int* __restrict__ dst, int* __restrict__ deg, int E) {
    int i = blockIdx.x * blockDim.x + threadIdx.x;
    if (i < E) atomicAdd(&deg[dst[i]], 1);
}
__global__ __launch_bounds__(256) void scan1_kernel(const int* __restrict__ deg, int* __restrict__ pre,
                                                    int* __restrict__ bsum, int n) {
    __shared__ int wsum[4];
    int t = threadIdx.x, lane = t & 63, w = t >> 6;
    int base = blockIdx.x * 1024 + t * 4;
    int v0 = base     < n ? deg[base]     : 0;
    int v1 = base + 1 < n ? deg[base + 1] : 0;
    int v2 = base + 2 < n ? deg[base + 2] : 0;
    int v3 = base + 3 < n ? deg[base + 3] : 0;
    int s = v0 + v1 + v2 + v3;
    int sc = s;
    #pragma unroll
    for (int o = 1; o < 64; o <<= 1) { int xx = __shfl_up(sc, o); if (lane >= o) sc += xx; }
    if (lane == 63) wsum[w] = sc;
    __syncthreads();
    int wo = 0;
    #pragma unroll
    for (int k = 0; k < 4; ++k) if (k < w) wo += wsum[k];
    int p = wo + sc - s;
    if (base     < n) pre[base]     = p; p += v0;
    if (base + 1 < n) pre[base + 1] = p; p += v1;
    if (base + 2 < n) pre[base + 2] = p; p += v2;
    if (base + 3 < n) pre[base + 3] = p;
    if (t == 255) bsum[blockIdx.x] = wo + sc;
}
__global__ void scan2_kernel(int* __restrict__ bsum, int nb) {
    int lane = threadIdx.x;
    int v = lane < nb ? bsum[lane] : 0;
    int sc = v;
    #pragma unroll
    for (int o = 1; o < 64; o <<= 1) { int xx = __shfl_up(sc, o); if (lane >= o) sc += xx; }
    if (lane < nb) bsum[lane] = sc - v;
}
__global__ void scan3_csr_kernel(const int* __restrict__ pre, const int* __restrict__ bsum,
                                 int* __restrict__ offsets, int* __restrict__ cursor,
                                 int* __restrict__ csr, int n, int total) {
    int i = blockIdx.x * 256 + threadIdx.x;
    if (i < n) {
        int off = pre[i] + bsum[i >> 10];
        offsets[i] = off;
        cursor[i] = off + 1;
        csr[off] = i;                                  // self-loop slot 0
    }
    if (i == 0) offsets[n] = total;
}
__global__ void scatter_kernel(const int* __restrict__ src, const int* __restrict__ dst,
                               int* __restrict__ cursor, int* __restrict__ csr, int E) {
    int i = blockIdx.x * blockDim.x + threadIdx.x;
    if (i < E) {
        int pos = atomicAdd(&cursor[dst[i]], 1);
        csr[pos] = src[i];
    }
}

// ---------------------------------------------------------------------------
// Aggregation: single edge pass, post-normalized softmax, fp8 gather payload.
// ---------------------------------------------------------------------------
__global__ void aggregate_kernel(const unsigned char* __restrict__ Hq,
                                 const float* __restrict__ alpha_src,
                                 const float* __restrict__ alpha_dst,
                                 const int* __restrict__ offsets,
                                 const int* __restrict__ csr,
                                 const float* __restrict__ b1, const float* __restrict__ b2,
                                 unsigned short* __restrict__ xcb, int N) {
    int n = (blockIdx.x * blockDim.x + threadIdx.x) >> 6;
    int lane = threadIdx.x & 63;
    if (n >= N) return;
    int beg = offsets[n], end = offsets[n + 1];
    int c0 = lane * 8;
    int hid = (lane < 32) ? (lane >> 3) : (4 + ((lane - 32) >> 2));
    float adh = alpha_dst[(size_t)n * AP + hid];

    float ssum = 0.f;
    float a0 = 0, a1 = 0, a2 = 0, a3 = 0, a4 = 0, a5 = 0, a6 = 0, a7 = 0;

    int i = beg;
    for (; i + 4 <= end; i += 4) {
        int ss[4];
        #pragma unroll
        for (int u = 0; u < 4; ++u) ss[u] = __builtin_nontemporal_load(csr + i + u);
        float lw[4];
        #pragma unroll
        for (int u = 0; u < 4; ++u) lw[u] = alpha_src[(size_t)ss[u] * AP + hid];
        uint2 hv[4];
        #pragma unroll
        for (int u = 0; u < 4; ++u) hv[u] = *(const uint2*)(Hq + (size_t)ss[u] * CC + c0);
        #pragma unroll
        for (int u = 0; u < 4; ++u) {
            float l = lw[u] + adh;
            l = l > 0.f ? l : 0.2f * l;
            float wv = __expf(l);
            ssum += wv;
            f32x2 p0 = __builtin_amdgcn_cvt_pk_f32_fp8(hv[u].x, false);
            f32x2 p1 = __builtin_amdgcn_cvt_pk_f32_fp8(hv[u].x, true);
            f32x2 p2 = __builtin_amdgcn_cvt_pk_f32_fp8(hv[u].y, false);
            f32x2 p3 = __builtin_amdgcn_cvt_pk_f32_fp8(hv[u].y, true);
            a0 += wv * p0[0]; a1 += wv * p0[1];
            a2 += wv * p1[0]; a3 += wv * p1[1];
            a4 += wv * p2[0]; a5 += wv * p2[1];
            a6 += wv * p3[0]; a7 += wv * p3[1];
        }
    }
    for (; i < end; ++i) {
        int s0 = __builtin_nontemporal_load(csr + i);
        float l = alpha_src[(size_t)s0 * AP + hid] + adh;
        uint2 hv0 = *(const uint2*)(Hq + (size_t)s0 * CC + c0);
        l = l > 0.f ? l : 0.2f * l;
        float wv = __expf(l);
        ssum += wv;
        f32x2 p0 = __builtin_amdgcn_cvt_pk_f32_fp8(hv0.x, false);
        f32x2 p1 = __builtin_amdgcn_cvt_pk_f32_fp8(hv0.x, true);
        f32x2 p2 = __builtin_amdgcn_cvt_pk_f32_fp8(hv0.y, false);
        f32x2 p3 = __builtin_amdgcn_cvt_pk_f32_fp8(hv0.y, true);
        a0 += wv * p0[0]; a1 += wv * p0[1];
        a2 += wv * p1[0]; a3 += wv * p1[1];
        a4 += wv * p2[0]; a5 += wv * p2[1];
        a6 += wv * p3[0]; a7 += wv * p3[1];
    }

    float inv = 1.0f / (ssum + 1e-16f);
    const float* bb = (c0 < 256) ? (b1 + c0) : (b2 + (c0 - 256));
    float4 bb0 = *(const float4*)(bb), bb1 = *(const float4*)(bb + 4);
    float o[8];
    o[0] = a0 * inv + bb0.x; o[1] = a1 * inv + bb0.y; o[2] = a2 * inv + bb0.z; o[3] = a3 * inv + bb0.w;
    o[4] = a4 * inv + bb1.x; o[5] = a5 * inv + bb1.y; o[6] = a6 * inv + bb1.z; o[7] = a7 * inv + bb1.w;
    #pragma unroll
    for (int j = 0; j < 8; ++j) o[j] = o[j] > 0.f ? o[j] : expm1f(o[j]);
    unsigned short u[8];
    #pragma unroll
    for (int j = 0; j < 8; ++j) u[j] = f2bf(o[j]);
    i32x4 pk;
    pk[0] = (int)((unsigned)u[0] | ((unsigned)u[1] << 16));
    pk[1] = (int)((unsigned)u[2] | ((unsigned)u[3] << 16));
    pk[2] = (int)((unsigned)u[4] | ((unsigned)u[5] << 16));
    pk[3] = (int)((unsigned)u[6] | ((unsigned)u[7] << 16));
    __builtin_nontemporal_store(pk, (i32x4*)(xcb + (size_t)n * CC + c0));
}

// ---------------------------------------------------------------------------
// Launch
// ---------------------------------------------------------------------------
extern "C" void kernel_launch(void* const* d_in, const int* in_sizes, int n_in,
                              void* d_out, int out_size, void* d_ws, size_t ws_size,
                              hipStream_t stream) {
    const float* x     = (const float*)d_in[0];
    const int*   ei    = (const int*)d_in[1];
    const float* gamma = (const float*)d_in[2];
    const float* beta  = (const float*)d_in[3];
    const float* W1    = (const float*)d_in[4];
    const float* as1   = (const float*)d_in[5];
    const float* ad1   = (const float*)d_in[6];
    const float* b1    = (const float*)d_in[7];
    const float* W2    = (const float*)d_in[8];
    const float* as2   = (const float*)d_in[9];
    const float* ad2   = (const float*)d_in[10];
    const float* b2    = (const float*)d_in[11];
    const float* Wu    = (const float*)d_in[12];
    const float* bu    = (const float*)d_in[13];
    float* out = (float*)d_out;

    const int N = in_sizes[0] / CH;
    const int E = in_sizes[1] / 2;
    const int* src = ei;
    const int* dst = ei + E;

    char* w = (char*)d_ws;
    auto alloc = [&](size_t bytes) { char* p = w; w += (bytes + 255) & ~(size_t)255; return p; };
    unsigned char*  Hq  = (unsigned char*)alloc((size_t)N * CC);
    unsigned short* xnb = (unsigned short*)alloc((size_t)N * CH * 2);
    unsigned short* xcb = (unsigned short*)alloc((size_t)N * CC * 2);
    unsigned short* WT1 = (unsigned short*)alloc(512 * 256 * 2);
    unsigned short* WTu = (unsigned short*)alloc(256 * 512 * 2);
    float* alpha_src = (float*)alloc((size_t)N * AP * 4);
    float* alpha_dst = (float*)alloc((size_t)N * AP * 4);
    int* deg     = (int*)alloc((size_t)N * 4);
    int* pre     = (int*)alloc((size_t)N * 4);
    int* bsum    = (int*)alloc(64 * 4);
    int* offsets = (int*)alloc(((size_t)N + 1) * 4);
    int* cursor  = (int*)alloc((size_t)N * 4);
    int* csr     = (int*)alloc(((size_t)E + N) * 4);

    const int LNB = (N + 3) / 4;
    const int DEGB = (N + 255) / 256;
    fused_pre_kernel<<<LNB + 1024 + DEGB, 256, 0, stream>>>(x, gamma, beta, W1, W2, Wu,
                                                            xnb, WT1, WTu, deg, N, LNB);

    const int MB = (N + 127) / 128;
    const int MB8 = ((MB + 7) / 8) * 8;
    gemm1_mfma<<<MB8 * 4, 256, 0, stream>>>(xnb, WT1, as1, ad1, as2, ad2,
                                            Hq, alpha_src, alpha_dst, N, MB);

    hist_kernel<<<(E + 255) / 256, 256, 0, stream>>>(dst, deg, E);
    int nb = (N + 1023) / 1024;
    scan1_kernel<<<nb, 256, 0, stream>>>(deg, pre, bsum, N);
    scan2_kernel<<<1, 64, 0, stream>>>(bsum, nb);
    scan3_csr_kernel<<<(N + 255) / 256, 256, 0, stream>>>(pre, bsum, offsets, cursor, csr, N, E + N);
    scatter_kernel<<<(E + 255) / 256, 256, 0, stream>>>(src, dst, cursor, csr, E);

    aggregate_kernel<<<(N + 3) / 4, 256, 0, stream>>>(Hq, alpha_src, alpha_dst, offsets, csr,
                                                      b1, b2, xcb, N);

    gemm2_mfma<<<MB8 * 2, 256, 0, stream>>>(xcb, WTu, bu, x, out, N, MB);
}

// Round 7
// 212.720 us; speedup vs baseline: 1.1595x; 1.0389x over previous
//
#include <hip/hip_runtime.h>
#include <hip/hip_bf16.h>
#include <math.h>

constexpr int CH = 256;       // input channels
constexpr int CC = 512;       // concat width
constexpr int AP = 16;        // padded alpha row stride (12 heads used)

typedef __bf16 bf16x8 __attribute__((ext_vector_type(8)));
typedef float  f32x4  __attribute__((ext_vector_type(4)));
typedef float  f32x2  __attribute__((ext_vector_type(2)));
typedef int    i32x4  __attribute__((ext_vector_type(4)));
typedef __attribute__((address_space(3))) void lds_void;
typedef __attribute__((address_space(1))) void glb_void;

__device__ inline unsigned short f2bf(float f) {
    union { float f; unsigned u; } v; v.f = f;
    unsigned r = v.u + 0x7FFFu + ((v.u >> 16) & 1u);
    return (unsigned short)(r >> 16);
}

// ---------------------------------------------------------------------------
// Fused pre-pass: LN(->bf16) + weight transpose/convert + deg init
// ---------------------------------------------------------------------------
__global__ void fused_pre_kernel(const float* __restrict__ x, const float* __restrict__ gamma,
                                 const float* __restrict__ beta,
                                 const float* __restrict__ W1, const float* __restrict__ W2,
                                 const float* __restrict__ Wu,
                                 unsigned short* __restrict__ xnb,
                                 unsigned short* __restrict__ WT1, unsigned short* __restrict__ WTu,
                                 int* __restrict__ deg, int N, int LNB) {
    int b = blockIdx.x;
    int t = threadIdx.x;
    if (b < LNB) {
        int wid = b * 4 + (t >> 6);
        int lane = t & 63;
        if (wid >= N) return;
        const float4 v = *(const float4*)(x + (size_t)wid * CH + lane * 4);
        float s = v.x + v.y + v.z + v.w;
        float sq = v.x * v.x + v.y * v.y + v.z * v.z + v.w * v.w;
        #pragma unroll
        for (int o = 32; o; o >>= 1) { s += __shfl_xor(s, o); sq += __shfl_xor(sq, o); }
        float mu = s * (1.0f / CH);
        float var = sq * (1.0f / CH) - mu * mu;
        float rs = rsqrtf(var + 1e-5f);
        float4 g = *(const float4*)(gamma + lane * 4);
        float4 bb = *(const float4*)(beta + lane * 4);
        unsigned short o0 = f2bf((v.x - mu) * rs * g.x + bb.x);
        unsigned short o1 = f2bf((v.y - mu) * rs * g.y + bb.y);
        unsigned short o2 = f2bf((v.z - mu) * rs * g.z + bb.z);
        unsigned short o3 = f2bf((v.w - mu) * rs * g.w + bb.w);
        uint2 pk;
        pk.x = (unsigned)o0 | ((unsigned)o1 << 16);
        pk.y = (unsigned)o2 | ((unsigned)o3 << 16);
        *(uint2*)(xnb + (size_t)wid * CH + lane * 4) = pk;
    } else if (b < LNB + 512) {
        int idx = (b - LNB) * 256 + t;              // 512*256
        int n = idx >> 8, k = idx & 255;
        float v = (n < 256) ? W1[(size_t)k * 256 + n] : W2[(size_t)k * 256 + (n - 256)];
        WT1[idx] = f2bf(v);
    } else if (b < LNB + 1024) {
        int idx = (b - LNB - 512) * 256 + t;        // 256*512
        int n = idx >> 9, k = idx & 511;
        WTu[idx] = f2bf(Wu[(size_t)k * 256 + n]);
    } else {
        int i = (b - LNB - 1024) * 256 + t;
        if (i < N) deg[i] = 1;                      // self-loop
    }
}

// ---------------------------------------------------------------------------
// bf16 MFMA GEMM core, 128x128 tile, BK=64, 4 waves, DOUBLE-BUFFERED LDS:
// stage(next) issued before compute(cur); single barrier per K-step so the
// next tile's global_load_lds completes under the current tile's MFMA.
// LDS XOR-swizzle via inverse-swizzled global source (global_load_lds linear).
// ---------------------------------------------------------------------------
template<int K>
__device__ inline void gemm_core_db(const unsigned short* __restrict__ Ab,
                                    const unsigned short* __restrict__ Bt,
                                    unsigned short* As, unsigned short* Bs,   // each [2][128*64]
                                    f32x4 acc[4][4], int m0, int n0, int M) {
    const int t = threadIdx.x;
    const int lane = t & 63;
    const int wave = t >> 6;
    const int wr = wave >> 1, wc = wave & 1;
    const int srow = lane >> 3;                        // 0..7
    const int scol = (((lane & 7) ^ srow) << 3);       // inverse-swizzled elem col
    const int fr = lane & 15;
    const int fkb = (lane >> 4) << 4;                  // logical colbyte per 16-lane group

    auto stage = [&](int buf, int k0) {
        #pragma unroll
        for (int c = 0; c < 4; ++c) {
            int chunk = c * 4 + wave;                  // 0..15 -> 8 rows each
            int row = chunk * 8 + srow;                // 0..127
            int gra = m0 + row; if (gra >= M) gra = M - 1;
            const unsigned short* ga = Ab + (size_t)gra * K + k0 + scol;
            __builtin_amdgcn_global_load_lds((const glb_void*)ga,
                                             (lds_void*)&As[buf * 8192 + chunk * 512], 16, 0, 0);
            const unsigned short* gb = Bt + (size_t)(n0 + row) * K + k0 + scol;
            __builtin_amdgcn_global_load_lds((const glb_void*)gb,
                                             (lds_void*)&Bs[buf * 8192 + chunk * 512], 16, 0, 0);
        }
    };
    auto compute = [&](int buf) {
        const int bb = buf * 16384;                    // byte offset
        #pragma unroll
        for (int ks = 0; ks < 2; ++ks) {
            bf16x8 af[4], bfr[4];
            #pragma unroll
            for (int m = 0; m < 4; ++m) {
                int r = wr * 64 + m * 16 + fr;
                int cb = (ks * 64 + fkb) ^ ((r & 7) << 4);
                af[m] = *(const bf16x8*)((const char*)As + bb + r * 128 + cb);
            }
            #pragma unroll
            for (int n = 0; n < 4; ++n) {
                int r = wc * 64 + n * 16 + fr;
                int cb = (ks * 64 + fkb) ^ ((r & 7) << 4);
                bfr[n] = *(const bf16x8*)((const char*)Bs + bb + r * 128 + cb);
            }
            #pragma unroll
            for (int m = 0; m < 4; ++m)
                #pragma unroll
                for (int n = 0; n < 4; ++n)
                    acc[m][n] = __builtin_amdgcn_mfma_f32_16x16x32_bf16(af[m], bfr[n], acc[m][n], 0, 0, 0);
        }
    };

    stage(0, 0);
    __syncthreads();
    int cur = 0;
    #pragma unroll
    for (int k0 = 64; k0 < K; k0 += 64) {
        stage(cur ^ 1, k0);     // issue next-tile loads
        compute(cur);           // MFMA on current tile (loads complete underneath)
        __syncthreads();        // drains vmcnt -> next buffer ready
        cur ^= 1;
    }
    compute(cur);               // tail (no prefetch)
}

// GEMM1: h(fp8 e4m3)[M,512] = xnorm @ WT1^T, fused alpha epilogue via
// LDS-transpose reduction (replaces 128-256 serial shfl chains).
__global__ __launch_bounds__(256) void gemm1_mfma(
    const unsigned short* __restrict__ Ab, const unsigned short* __restrict__ Bt,
    const float* __restrict__ as1, const float* __restrict__ ad1,
    const float* __restrict__ as2, const float* __restrict__ ad2,
    unsigned char* __restrict__ Hq,
    float* __restrict__ alpha_src, float* __restrict__ alpha_dst, int M, int MB) {
    __shared__ unsigned short As[2 * 128 * 64];
    __shared__ unsigned short Bs[2 * 128 * 64];
    const int s = blockIdx.x;
    const int xcd = s & 7;
    const int jj = s >> 3;
    const int n_blk = jj & 3;                          // NB=4
    const int m_blk = (jj >> 2) * 8 + xcd;
    if (m_blk >= MB) return;
    const int m0 = m_blk * 128, n0 = n_blk * 128;
    const int lane = threadIdx.x & 63;
    const int wave = threadIdx.x >> 6;
    const int wr = wave >> 1, wc = wave & 1;
    f32x4 acc[4][4] = {};
    gemm_core_db<256>(Ab, Bt, As, Bs, acc, m0, n0, M);
    const int fr = lane & 15;
    const int orow = (lane >> 4) * 4;
    // H store as fp8 e4m3
    #pragma unroll
    for (int m = 0; m < 4; ++m)
        #pragma unroll
        for (int j = 0; j < 4; ++j) {
            int r = m0 + wr * 64 + m * 16 + orow + j;
            if (r < M) {
                #pragma unroll
                for (int n = 0; n < 4; ++n) {
                    int ccol = n0 + wc * 64 + n * 16 + fr;
                    unsigned q = (unsigned)__builtin_amdgcn_cvt_pk_fp8_f32(
                        acc[m][n][j], acc[m][n][j], 0, false) & 0xffu;
                    Hq[(size_t)r * CC + ccol] = (unsigned char)q;
                }
            }
        }
    // ---- alpha epilogue: LDS-transpose reduction over the 16-lane (fr) dim ----
    const int colbase = n0 + wc * 64;
    const bool gat1 = colbase < 256;
    f32x4 svv, dvv;
    int headA;
    if (gat1) {
        headA = colbase >> 6;
        #pragma unroll
        for (int n = 0; n < 4; ++n) { int c = colbase + n * 16 + fr; svv[n] = as1[c]; dvv[n] = ad1[c]; }
    } else {
        headA = 4 + ((colbase - 256) >> 5);
        #pragma unroll
        for (int n = 0; n < 4; ++n) { int c = colbase - 256 + n * 16 + fr; svv[n] = as2[c]; dvv[n] = ad2[c]; }
    }
    __syncthreads();                                    // all waves done reading As
    float* S = (float*)As + wave * 1024;                // 64 lanes x 16 floats per wave
    const int g = lane >> 4, kslot = lane & 15;
    const int rown = m0 + wr * 64 + (kslot >> 2) * 16 + g * 4 + (kslot & 3);
    const bool rok = rown < M;
    auto xpose_reduce = [&](f32x4 q0, f32x4 q1, f32x4 q2, f32x4 q3) -> float {
        float* base = S + lane * 16;
        *(f32x4*)(base + 0)  = q0;
        *(f32x4*)(base + 4)  = q1;
        *(f32x4*)(base + 8)  = q2;
        *(f32x4*)(base + 12) = q3;
        const float* rb = S + g * 256 + kslot;
        float sum = 0.f;
        #pragma unroll
        for (int f = 0; f < 16; ++f) sum += rb[f * 16];
        return sum;
    };
    #define PARTF(m, j, W)  (acc[m][0][j]*W[0] + acc[m][1][j]*W[1] + acc[m][2][j]*W[2] + acc[m][3][j]*W[3])
    #define PART01(m, j, W) (acc[m][0][j]*W[0] + acc[m][1][j]*W[1])
    #define PART23(m, j, W) (acc[m][2][j]*W[2] + acc[m][3][j]*W[3])
    #define QUADF(m, W)  (f32x4){PARTF(m,0,W), PARTF(m,1,W), PARTF(m,2,W), PARTF(m,3,W)}
    #define QUAD01(m, W) (f32x4){PART01(m,0,W), PART01(m,1,W), PART01(m,2,W), PART01(m,3,W)}
    #define QUAD23(m, W) (f32x4){PART23(m,0,W), PART23(m,1,W), PART23(m,2,W), PART23(m,3,W)}
    if (gat1) {
        float ts = xpose_reduce(QUADF(0, svv), QUADF(1, svv), QUADF(2, svv), QUADF(3, svv));
        if (rok) alpha_src[(size_t)rown * AP + headA] = ts;
        float td = xpose_reduce(QUADF(0, dvv), QUADF(1, dvv), QUADF(2, dvv), QUADF(3, dvv));
        if (rok) alpha_dst[(size_t)rown * AP + headA] = td;
    } else {
        float s01 = xpose_reduce(QUAD01(0, svv), QUAD01(1, svv), QUAD01(2, svv), QUAD01(3, svv));
        if (rok) alpha_src[(size_t)rown * AP + headA] = s01;
        float s23 = xpose_reduce(QUAD23(0, svv), QUAD23(1, svv), QUAD23(2, svv), QUAD23(3, svv));
        if (rok) alpha_src[(size_t)rown * AP + headA + 1] = s23;
        float d01 = xpose_reduce(QUAD01(0, dvv), QUAD01(1, dvv), QUAD01(2, dvv), QUAD01(3, dvv));
        if (rok) alpha_dst[(size_t)rown * AP + headA] = d01;
        float d23 = xpose_reduce(QUAD23(0, dvv), QUAD23(1, dvv), QUAD23(2, dvv), QUAD23(3, dvv));
        if (rok) alpha_dst[(size_t)rown * AP + headA + 1] = d23;
    }
    #undef PARTF
    #undef PART01
    #undef PART23
    #undef QUADF
    #undef QUAD01
    #undef QUAD23
}

// GEMM2: out(f32)[M,256] = x + xcat(bf16) @ WTu^T + bu  (nt residual/out)
__global__ __launch_bounds__(256) void gemm2_mfma(const unsigned short* __restrict__ Ab,
                                                  const unsigned short* __restrict__ Bt,
                                                  const float* __restrict__ bu,
                                                  const float* __restrict__ xres,
                                                  float* __restrict__ C, int M, int MB) {
    __shared__ unsigned short As[2 * 128 * 64];
    __shared__ unsigned short Bs[2 * 128 * 64];
    const int s = blockIdx.x;
    const int xcd = s & 7;
    const int jj = s >> 3;
    const int n_blk = jj & 1;                          // NB=2
    const int m_blk = (jj >> 1) * 8 + xcd;
    if (m_blk >= MB) return;
    const int m0 = m_blk * 128, n0 = n_blk * 128;
    const int lane = threadIdx.x & 63;
    const int wave = threadIdx.x >> 6;
    const int wr = wave >> 1, wc = wave & 1;
    f32x4 acc[4][4] = {};
    gemm_core_db<512>(Ab, Bt, As, Bs, acc, m0, n0, M);
    const int fr = lane & 15;
    const int orow = (lane >> 4) * 4;
    #pragma unroll
    for (int m = 0; m < 4; ++m)
        #pragma unroll
        for (int j = 0; j < 4; ++j) {
            int r = m0 + wr * 64 + m * 16 + orow + j;
            if (r < M) {
                #pragma unroll
                for (int n = 0; n < 4; ++n) {
                    int ccol = n0 + wc * 64 + n * 16 + fr;
                    float xr = __builtin_nontemporal_load(&xres[(size_t)r * CH + ccol]);
                    __builtin_nontemporal_store(acc[m][n][j] + bu[ccol] + xr,
                                                &C[(size_t)r * CH + ccol]);
                }
            }
        }
}

// ---------------------------------------------------------------------------
// CSR build
// ---------------------------------------------------------------------------
__global__ void hist_kernel(const int* __restrict__ dst, int* __restrict__ deg, int E) {
    int i = blockIdx.x * blockDim.x + threadIdx.x;
    if (i < E) atomicAdd(&deg[dst[i]], 1);
}
__global__ __launch_bounds__(256) void scan1_kernel(const int* __restrict__ deg, int* __restrict__ pre,
                                                    int* __restrict__ bsum, int n) {
    __shared__ int wsum[4];
    int t = threadIdx.x, lane = t & 63, w = t >> 6;
    int base = blockIdx.x * 1024 + t * 4;
    int v0 = base     < n ? deg[base]     : 0;
    int v1 = base + 1 < n ? deg[base + 1] : 0;
    int v2 = base + 2 < n ? deg[base + 2] : 0;
    int v3 = base + 3 < n ? deg[base + 3] : 0;
    int s = v0 + v1 + v2 + v3;
    int sc = s;
    #pragma unroll
    for (int o = 1; o < 64; o <<= 1) { int xx = __shfl_up(sc, o); if (lane >= o) sc += xx; }
    if (lane == 63) wsum[w] = sc;
    __syncthreads();
    int wo = 0;
    #pragma unroll
    for (int k = 0; k < 4; ++k) if (k < w) wo += wsum[k];
    int p = wo + sc - s;
    if (base     < n) pre[base]     = p; p += v0;
    if (base + 1 < n) pre[base + 1] = p; p += v1;
    if (base + 2 < n) pre[base + 2] = p; p += v2;
    if (base + 3 < n) pre[base + 3] = p;
    if (t == 255) bsum[blockIdx.x] = wo + sc;
}
__global__ void scan2_kernel(int* __restrict__ bsum, int nb) {
    int lane = threadIdx.x;
    int v = lane < nb ? bsum[lane] : 0;
    int sc = v;
    #pragma unroll
    for (int o = 1; o < 64; o <<= 1) { int xx = __shfl_up(sc, o); if (lane >= o) sc += xx; }
    if (lane < nb) bsum[lane] = sc - v;
}
__global__ void scan3_csr_kernel(const int* __restrict__ pre, const int* __restrict__ bsum,
                                 int* __restrict__ offsets, int* __restrict__ cursor,
                                 int* __restrict__ csr, int n, int total) {
    int i = blockIdx.x * 256 + threadIdx.x;
    if (i < n) {
        int off = pre[i] + bsum[i >> 10];
        offsets[i] = off;
        cursor[i] = off + 1;
        csr[off] = i;                                  // self-loop slot 0
    }
    if (i == 0) offsets[n] = total;
}
__global__ void scatter_kernel(const int* __restrict__ src, const int* __restrict__ dst,
                               int* __restrict__ cursor, int* __restrict__ csr, int E) {
    int i = blockIdx.x * blockDim.x + threadIdx.x;
    if (i < E) {
        int pos = atomicAdd(&cursor[dst[i]], 1);
        csr[pos] = src[i];
    }
}

// ---------------------------------------------------------------------------
// Aggregation: single edge pass, post-normalized softmax, fp8 gather payload.
// ---------------------------------------------------------------------------
__global__ void aggregate_kernel(const unsigned char* __restrict__ Hq,
                                 const float* __restrict__ alpha_src,
                                 const float* __restrict__ alpha_dst,
                                 const int* __restrict__ offsets,
                                 const int* __restrict__ csr,
                                 const float* __restrict__ b1, const float* __restrict__ b2,
                                 unsigned short* __restrict__ xcb, int N) {
    int n = (blockIdx.x * blockDim.x + threadIdx.x) >> 6;
    int lane = threadIdx.x & 63;
    if (n >= N) return;
    int beg = offsets[n], end = offsets[n + 1];
    int c0 = lane * 8;
    int hid = (lane < 32) ? (lane >> 3) : (4 + ((lane - 32) >> 2));
    float adh = alpha_dst[(size_t)n * AP + hid];

    float ssum = 0.f;
    float a0 = 0, a1 = 0, a2 = 0, a3 = 0, a4 = 0, a5 = 0, a6 = 0, a7 = 0;

    int i = beg;
    for (; i + 4 <= end; i += 4) {
        int ss[4];
        #pragma unroll
        for (int u = 0; u < 4; ++u) ss[u] = __builtin_nontemporal_load(csr + i + u);
        float lw[4];
        #pragma unroll
        for (int u = 0; u < 4; ++u) lw[u] = alpha_src[(size_t)ss[u] * AP + hid];
        uint2 hv[4];
        #pragma unroll
        for (int u = 0; u < 4; ++u) hv[u] = *(const uint2*)(Hq + (size_t)ss[u] * CC + c0);
        #pragma unroll
        for (int u = 0; u < 4; ++u) {
            float l = lw[u] + adh;
            l = l > 0.f ? l : 0.2f * l;
            float wv = __expf(l);
            ssum += wv;
            f32x2 p0 = __builtin_amdgcn_cvt_pk_f32_fp8(hv[u].x, false);
            f32x2 p1 = __builtin_amdgcn_cvt_pk_f32_fp8(hv[u].x, true);
            f32x2 p2 = __builtin_amdgcn_cvt_pk_f32_fp8(hv[u].y, false);
            f32x2 p3 = __builtin_amdgcn_cvt_pk_f32_fp8(hv[u].y, true);
            a0 += wv * p0[0]; a1 += wv * p0[1];
            a2 += wv * p1[0]; a3 += wv * p1[1];
            a4 += wv * p2[0]; a5 += wv * p2[1];
            a6 += wv * p3[0]; a7 += wv * p3[1];
        }
    }
    for (; i < end; ++i) {
        int s0 = __builtin_nontemporal_load(csr + i);
        float l = alpha_src[(size_t)s0 * AP + hid] + adh;
        uint2 hv0 = *(const uint2*)(Hq + (size_t)s0 * CC + c0);
        l = l > 0.f ? l : 0.2f * l;
        float wv = __expf(l);
        ssum += wv;
        f32x2 p0 = __builtin_amdgcn_cvt_pk_f32_fp8(hv0.x, false);
        f32x2 p1 = __builtin_amdgcn_cvt_pk_f32_fp8(hv0.x, true);
        f32x2 p2 = __builtin_amdgcn_cvt_pk_f32_fp8(hv0.y, false);
        f32x2 p3 = __builtin_amdgcn_cvt_pk_f32_fp8(hv0.y, true);
        a0 += wv * p0[0]; a1 += wv * p0[1];
        a2 += wv * p1[0]; a3 += wv * p1[1];
        a4 += wv * p2[0]; a5 += wv * p2[1];
        a6 += wv * p3[0]; a7 += wv * p3[1];
    }

    float inv = 1.0f / (ssum + 1e-16f);
    const float* bb = (c0 < 256) ? (b1 + c0) : (b2 + (c0 - 256));
    float4 bb0 = *(const float4*)(bb), bb1 = *(const float4*)(bb + 4);
    float o[8];
    o[0] = a0 * inv + bb0.x; o[1] = a1 * inv + bb0.y; o[2] = a2 * inv + bb0.z; o[3] = a3 * inv + bb0.w;
    o[4] = a4 * inv + bb1.x; o[5] = a5 * inv + bb1.y; o[6] = a6 * inv + bb1.z; o[7] = a7 * inv + bb1.w;
    #pragma unroll
    for (int j = 0; j < 8; ++j) o[j] = o[j] > 0.f ? o[j] : expm1f(o[j]);
    unsigned short u[8];
    #pragma unroll
    for (int j = 0; j < 8; ++j) u[j] = f2bf(o[j]);
    i32x4 pk;
    pk[0] = (int)((unsigned)u[0] | ((unsigned)u[1] << 16));
    pk[1] = (int)((unsigned)u[2] | ((unsigned)u[3] << 16));
    pk[2] = (int)((unsigned)u[4] | ((unsigned)u[5] << 16));
    pk[3] = (int)((unsigned)u[6] | ((unsigned)u[7] << 16));
    __builtin_nontemporal_store(pk, (i32x4*)(xcb + (size_t)n * CC + c0));
}

// ---------------------------------------------------------------------------
// Launch
// ---------------------------------------------------------------------------
extern "C" void kernel_launch(void* const* d_in, const int* in_sizes, int n_in,
                              void* d_out, int out_size, void* d_ws, size_t ws_size,
                              hipStream_t stream) {
    const float* x     = (const float*)d_in[0];
    const int*   ei    = (const int*)d_in[1];
    const float* gamma = (const float*)d_in[2];
    const float* beta  = (const float*)d_in[3];
    const float* W1    = (const float*)d_in[4];
    const float* as1   = (const float*)d_in[5];
    const float* ad1   = (const float*)d_in[6];
    const float* b1    = (const float*)d_in[7];
    const float* W2    = (const float*)d_in[8];
    const float* as2   = (const float*)d_in[9];
    const float* ad2   = (const float*)d_in[10];
    const float* b2    = (const float*)d_in[11];
    const float* Wu    = (const float*)d_in[12];
    const float* bu    = (const float*)d_in[13];
    float* out = (float*)d_out;

    const int N = in_sizes[0] / CH;
    const int E = in_sizes[1] / 2;
    const int* src = ei;
    const int* dst = ei + E;

    char* w = (char*)d_ws;
    auto alloc = [&](size_t bytes) { char* p = w; w += (bytes + 255) & ~(size_t)255; return p; };
    unsigned char*  Hq  = (unsigned char*)alloc((size_t)N * CC);
    unsigned short* xnb = (unsigned short*)alloc((size_t)N * CH * 2);
    unsigned short* xcb = (unsigned short*)alloc((size_t)N * CC * 2);
    unsigned short* WT1 = (unsigned short*)alloc(512 * 256 * 2);
    unsigned short* WTu = (unsigned short*)alloc(256 * 512 * 2);
    float* alpha_src = (float*)alloc((size_t)N * AP * 4);
    float* alpha_dst = (float*)alloc((size_t)N * AP * 4);
    int* deg     = (int*)alloc((size_t)N * 4);
    int* pre     = (int*)alloc((size_t)N * 4);
    int* bsum    = (int*)alloc(64 * 4);
    int* offsets = (int*)alloc(((size_t)N + 1) * 4);
    int* cursor  = (int*)alloc((size_t)N * 4);
    int* csr     = (int*)alloc(((size_t)E + N) * 4);

    const int LNB = (N + 3) / 4;
    const int DEGB = (N + 255) / 256;
    fused_pre_kernel<<<LNB + 1024 + DEGB, 256, 0, stream>>>(x, gamma, beta, W1, W2, Wu,
                                                            xnb, WT1, WTu, deg, N, LNB);

    const int MB = (N + 127) / 128;
    const int MB8 = ((MB + 7) / 8) * 8;
    gemm1_mfma<<<MB8 * 4, 256, 0, stream>>>(xnb, WT1, as1, ad1, as2, ad2,
                                            Hq, alpha_src, alpha_dst, N, MB);

    hist_kernel<<<(E + 255) / 256, 256, 0, stream>>>(dst, deg, E);
    int nb = (N + 1023) / 1024;
    scan1_kernel<<<nb, 256, 0, stream>>>(deg, pre, bsum, N);
    scan2_kernel<<<1, 64, 0, stream>>>(bsum, nb);
    scan3_csr_kernel<<<(N + 255) / 256, 256, 0, stream>>>(pre, bsum, offsets, cursor, csr, N, E + N);
    scatter_kernel<<<(E + 255) / 256, 256, 0, stream>>>(src, dst, cursor, csr, E);

    aggregate_kernel<<<(N + 3) / 4, 256, 0, stream>>>(Hq, alpha_src, alpha_dst, offsets, csr,
                                                      b1, b2, xcb, N);

    gemm2_mfma<<<MB8 * 2, 256, 0, stream>>>(xcb, WTu, bu, x, out, N, MB);
}

// Round 8
// 198.704 us; speedup vs baseline: 1.2412x; 1.0705x over previous
//
#include <hip/hip_runtime.h>
#include <hip/hip_bf16.h>
#include <math.h>

constexpr int CH = 256;       // input channels
constexpr int CC = 512;       // concat width
constexpr int AP = 16;        // padded alpha row stride (12 heads used)

typedef __bf16 bf16x8 __attribute__((ext_vector_type(8)));
typedef float  f32x4  __attribute__((ext_vector_type(4)));
typedef float  f32x2  __attribute__((ext_vector_type(2)));
typedef int    i32x4  __attribute__((ext_vector_type(4)));
typedef __attribute__((address_space(3))) void lds_void;
typedef __attribute__((address_space(1))) void glb_void;

__device__ inline unsigned short f2bf(float f) {
    union { float f; unsigned u; } v; v.f = f;
    unsigned r = v.u + 0x7FFFu + ((v.u >> 16) & 1u);
    return (unsigned short)(r >> 16);
}

// ---------------------------------------------------------------------------
// Fused pre-pass: LN(->bf16) + weight transpose/convert + deg init
// ---------------------------------------------------------------------------
__global__ void fused_pre_kernel(const float* __restrict__ x, const float* __restrict__ gamma,
                                 const float* __restrict__ beta,
                                 const float* __restrict__ W1, const float* __restrict__ W2,
                                 const float* __restrict__ Wu,
                                 unsigned short* __restrict__ xnb,
                                 unsigned short* __restrict__ WT1, unsigned short* __restrict__ WTu,
                                 int* __restrict__ deg, int N, int LNB) {
    int b = blockIdx.x;
    int t = threadIdx.x;
    if (b < LNB) {
        int wid = b * 4 + (t >> 6);
        int lane = t & 63;
        if (wid >= N) return;
        const float4 v = *(const float4*)(x + (size_t)wid * CH + lane * 4);
        float s = v.x + v.y + v.z + v.w;
        float sq = v.x * v.x + v.y * v.y + v.z * v.z + v.w * v.w;
        #pragma unroll
        for (int o = 32; o; o >>= 1) { s += __shfl_xor(s, o); sq += __shfl_xor(sq, o); }
        float mu = s * (1.0f / CH);
        float var = sq * (1.0f / CH) - mu * mu;
        float rs = rsqrtf(var + 1e-5f);
        float4 g = *(const float4*)(gamma + lane * 4);
        float4 bb = *(const float4*)(beta + lane * 4);
        unsigned short o0 = f2bf((v.x - mu) * rs * g.x + bb.x);
        unsigned short o1 = f2bf((v.y - mu) * rs * g.y + bb.y);
        unsigned short o2 = f2bf((v.z - mu) * rs * g.z + bb.z);
        unsigned short o3 = f2bf((v.w - mu) * rs * g.w + bb.w);
        uint2 pk;
        pk.x = (unsigned)o0 | ((unsigned)o1 << 16);
        pk.y = (unsigned)o2 | ((unsigned)o3 << 16);
        *(uint2*)(xnb + (size_t)wid * CH + lane * 4) = pk;
    } else if (b < LNB + 512) {
        int idx = (b - LNB) * 256 + t;              // 512*256
        int n = idx >> 8, k = idx & 255;
        float v = (n < 256) ? W1[(size_t)k * 256 + n] : W2[(size_t)k * 256 + (n - 256)];
        WT1[idx] = f2bf(v);
    } else if (b < LNB + 1024) {
        int idx = (b - LNB - 512) * 256 + t;        // 256*512
        int n = idx >> 9, k = idx & 511;
        WTu[idx] = f2bf(Wu[(size_t)k * 256 + n]);
    } else {
        int i = (b - LNB - 1024) * 256 + t;
        if (i < N) deg[i] = 1;                      // self-loop
    }
}

// ---------------------------------------------------------------------------
// bf16 MFMA GEMM core, 128x128 tile, BK=64, 4 waves, double-buffered LDS.
// LDS XOR-swizzle via inverse-swizzled global source (global_load_lds linear).
// ---------------------------------------------------------------------------
template<int K>
__device__ inline void gemm_core_db(const unsigned short* __restrict__ Ab,
                                    const unsigned short* __restrict__ Bt,
                                    unsigned short* As, unsigned short* Bs,   // each [2][128*64]
                                    f32x4 acc[4][4], int m0, int n0, int M) {
    const int t = threadIdx.x;
    const int lane = t & 63;
    const int wave = t >> 6;
    const int wr = wave >> 1, wc = wave & 1;
    const int srow = lane >> 3;                        // 0..7
    const int scol = (((lane & 7) ^ srow) << 3);       // inverse-swizzled elem col
    const int fr = lane & 15;
    const int fkb = (lane >> 4) << 4;                  // logical colbyte per 16-lane group

    auto stage = [&](int buf, int k0) {
        #pragma unroll
        for (int c = 0; c < 4; ++c) {
            int chunk = c * 4 + wave;                  // 0..15 -> 8 rows each
            int row = chunk * 8 + srow;                // 0..127
            int gra = m0 + row; if (gra >= M) gra = M - 1;
            const unsigned short* ga = Ab + (size_t)gra * K + k0 + scol;
            __builtin_amdgcn_global_load_lds((const glb_void*)ga,
                                             (lds_void*)&As[buf * 8192 + chunk * 512], 16, 0, 0);
            const unsigned short* gb = Bt + (size_t)(n0 + row) * K + k0 + scol;
            __builtin_amdgcn_global_load_lds((const glb_void*)gb,
                                             (lds_void*)&Bs[buf * 8192 + chunk * 512], 16, 0, 0);
        }
    };
    auto compute = [&](int buf) {
        const int bb = buf * 16384;                    // byte offset
        #pragma unroll
        for (int ks = 0; ks < 2; ++ks) {
            bf16x8 af[4], bfr[4];
            #pragma unroll
            for (int m = 0; m < 4; ++m) {
                int r = wr * 64 + m * 16 + fr;
                int cb = (ks * 64 + fkb) ^ ((r & 7) << 4);
                af[m] = *(const bf16x8*)((const char*)As + bb + r * 128 + cb);
            }
            #pragma unroll
            for (int n = 0; n < 4; ++n) {
                int r = wc * 64 + n * 16 + fr;
                int cb = (ks * 64 + fkb) ^ ((r & 7) << 4);
                bfr[n] = *(const bf16x8*)((const char*)Bs + bb + r * 128 + cb);
            }
            #pragma unroll
            for (int m = 0; m < 4; ++m)
                #pragma unroll
                for (int n = 0; n < 4; ++n)
                    acc[m][n] = __builtin_amdgcn_mfma_f32_16x16x32_bf16(af[m], bfr[n], acc[m][n], 0, 0, 0);
        }
    };

    stage(0, 0);
    __syncthreads();
    int cur = 0;
    #pragma unroll
    for (int k0 = 64; k0 < K; k0 += 64) {
        stage(cur ^ 1, k0);     // issue next-tile loads
        compute(cur);           // MFMA on current tile (loads complete underneath)
        __syncthreads();        // drains vmcnt -> next buffer ready
        cur ^= 1;
    }
    compute(cur);               // tail (no prefetch)
}

// GEMM1: h(fp8 e4m3)[M,512] = xnorm @ WT1^T, fused alpha epilogue via LDS
// transpose; trailing blocks (>= G1B) run the degree histogram (fused launch).
__global__ __launch_bounds__(256) void gemm1_mfma(
    const unsigned short* __restrict__ Ab, const unsigned short* __restrict__ Bt,
    const float* __restrict__ as1, const float* __restrict__ ad1,
    const float* __restrict__ as2, const float* __restrict__ ad2,
    unsigned char* __restrict__ Hq,
    float* __restrict__ alpha_src, float* __restrict__ alpha_dst, int M, int MB,
    const int* __restrict__ dstE, int* __restrict__ deg, int E, int G1B) {
    __shared__ unsigned short As[2 * 128 * 64];
    __shared__ unsigned short Bs[2 * 128 * 64];
    const int s = blockIdx.x;
    if (s >= G1B) {                                    // fused histogram blocks
        int i = (s - G1B) * 256 + threadIdx.x;
        if (i < E) atomicAdd(&deg[dstE[i]], 1);
        return;
    }
    const int xcd = s & 7;
    const int jj = s >> 3;
    const int n_blk = jj & 3;                          // NB=4
    const int m_blk = (jj >> 2) * 8 + xcd;
    if (m_blk >= MB) return;
    const int m0 = m_blk * 128, n0 = n_blk * 128;
    const int lane = threadIdx.x & 63;
    const int wave = threadIdx.x >> 6;
    const int wr = wave >> 1, wc = wave & 1;
    f32x4 acc[4][4] = {};
    gemm_core_db<256>(Ab, Bt, As, Bs, acc, m0, n0, M);
    const int fr = lane & 15;
    const int orow = (lane >> 4) * 4;
    // H store as fp8 e4m3
    #pragma unroll
    for (int m = 0; m < 4; ++m)
        #pragma unroll
        for (int j = 0; j < 4; ++j) {
            int r = m0 + wr * 64 + m * 16 + orow + j;
            if (r < M) {
                #pragma unroll
                for (int n = 0; n < 4; ++n) {
                    int ccol = n0 + wc * 64 + n * 16 + fr;
                    unsigned q = (unsigned)__builtin_amdgcn_cvt_pk_fp8_f32(
                        acc[m][n][j], acc[m][n][j], 0, false) & 0xffu;
                    Hq[(size_t)r * CC + ccol] = (unsigned char)q;
                }
            }
        }
    // ---- alpha epilogue: LDS-transpose reduction over the 16-lane (fr) dim ----
    const int colbase = n0 + wc * 64;
    const bool gat1 = colbase < 256;
    f32x4 svv, dvv;
    int headA;
    if (gat1) {
        headA = colbase >> 6;
        #pragma unroll
        for (int n = 0; n < 4; ++n) { int c = colbase + n * 16 + fr; svv[n] = as1[c]; dvv[n] = ad1[c]; }
    } else {
        headA = 4 + ((colbase - 256) >> 5);
        #pragma unroll
        for (int n = 0; n < 4; ++n) { int c = colbase - 256 + n * 16 + fr; svv[n] = as2[c]; dvv[n] = ad2[c]; }
    }
    __syncthreads();                                    // all waves done reading As
    float* S = (float*)As + wave * 1024;                // 64 lanes x 16 floats per wave
    const int g = lane >> 4, kslot = lane & 15;
    const int rown = m0 + wr * 64 + (kslot >> 2) * 16 + g * 4 + (kslot & 3);
    const bool rok = rown < M;
    auto xpose_reduce = [&](f32x4 q0, f32x4 q1, f32x4 q2, f32x4 q3) -> float {
        float* base = S + lane * 16;
        *(f32x4*)(base + 0)  = q0;
        *(f32x4*)(base + 4)  = q1;
        *(f32x4*)(base + 8)  = q2;
        *(f32x4*)(base + 12) = q3;
        const float* rb = S + g * 256 + kslot;
        float sum = 0.f;
        #pragma unroll
        for (int f = 0; f < 16; ++f) sum += rb[f * 16];
        return sum;
    };
    #define PARTF(m, j, W)  (acc[m][0][j]*W[0] + acc[m][1][j]*W[1] + acc[m][2][j]*W[2] + acc[m][3][j]*W[3])
    #define PART01(m, j, W) (acc[m][0][j]*W[0] + acc[m][1][j]*W[1])
    #define PART23(m, j, W) (acc[m][2][j]*W[2] + acc[m][3][j]*W[3])
    #define QUADF(m, W)  (f32x4){PARTF(m,0,W), PARTF(m,1,W), PARTF(m,2,W), PARTF(m,3,W)}
    #define QUAD01(m, W) (f32x4){PART01(m,0,W), PART01(m,1,W), PART01(m,2,W), PART01(m,3,W)}
    #define QUAD23(m, W) (f32x4){PART23(m,0,W), PART23(m,1,W), PART23(m,2,W), PART23(m,3,W)}
    if (gat1) {
        float ts = xpose_reduce(QUADF(0, svv), QUADF(1, svv), QUADF(2, svv), QUADF(3, svv));
        if (rok) alpha_src[(size_t)rown * AP + headA] = ts;
        float td = xpose_reduce(QUADF(0, dvv), QUADF(1, dvv), QUADF(2, dvv), QUADF(3, dvv));
        if (rok) alpha_dst[(size_t)rown * AP + headA] = td;
    } else {
        float s01 = xpose_reduce(QUAD01(0, svv), QUAD01(1, svv), QUAD01(2, svv), QUAD01(3, svv));
        if (rok) alpha_src[(size_t)rown * AP + headA] = s01;
        float s23 = xpose_reduce(QUAD23(0, svv), QUAD23(1, svv), QUAD23(2, svv), QUAD23(3, svv));
        if (rok) alpha_src[(size_t)rown * AP + headA + 1] = s23;
        float d01 = xpose_reduce(QUAD01(0, dvv), QUAD01(1, dvv), QUAD01(2, dvv), QUAD01(3, dvv));
        if (rok) alpha_dst[(size_t)rown * AP + headA] = d01;
        float d23 = xpose_reduce(QUAD23(0, dvv), QUAD23(1, dvv), QUAD23(2, dvv), QUAD23(3, dvv));
        if (rok) alpha_dst[(size_t)rown * AP + headA + 1] = d23;
    }
    #undef PARTF
    #undef PART01
    #undef PART23
    #undef QUADF
    #undef QUAD01
    #undef QUAD23
}

// GEMM2: out(f32)[M,256] = x + xcat(bf16) @ WTu^T + bu  (nt residual/out)
__global__ __launch_bounds__(256) void gemm2_mfma(const unsigned short* __restrict__ Ab,
                                                  const unsigned short* __restrict__ Bt,
                                                  const float* __restrict__ bu,
                                                  const float* __restrict__ xres,
                                                  float* __restrict__ C, int M, int MB) {
    __shared__ unsigned short As[2 * 128 * 64];
    __shared__ unsigned short Bs[2 * 128 * 64];
    const int s = blockIdx.x;
    const int xcd = s & 7;
    const int jj = s >> 3;
    const int n_blk = jj & 1;                          // NB=2
    const int m_blk = (jj >> 1) * 8 + xcd;
    if (m_blk >= MB) return;
    const int m0 = m_blk * 128, n0 = n_blk * 128;
    const int lane = threadIdx.x & 63;
    const int wave = threadIdx.x >> 6;
    const int wr = wave >> 1, wc = wave & 1;
    f32x4 acc[4][4] = {};
    gemm_core_db<512>(Ab, Bt, As, Bs, acc, m0, n0, M);
    const int fr = lane & 15;
    const int orow = (lane >> 4) * 4;
    #pragma unroll
    for (int m = 0; m < 4; ++m)
        #pragma unroll
        for (int j = 0; j < 4; ++j) {
            int r = m0 + wr * 64 + m * 16 + orow + j;
            if (r < M) {
                #pragma unroll
                for (int n = 0; n < 4; ++n) {
                    int ccol = n0 + wc * 64 + n * 16 + fr;
                    float xr = __builtin_nontemporal_load(&xres[(size_t)r * CH + ccol]);
                    __builtin_nontemporal_store(acc[m][n][j] + bu[ccol] + xr,
                                                &C[(size_t)r * CH + ccol]);
                }
            }
        }
}

// ---------------------------------------------------------------------------
// CSR build
// ---------------------------------------------------------------------------
__global__ __launch_bounds__(256) void scan1_kernel(const int* __restrict__ deg, int* __restrict__ pre,
                                                    int* __restrict__ bsum, int n) {
    __shared__ int wsum[4];
    int t = threadIdx.x, lane = t & 63, w = t >> 6;
    int base = blockIdx.x * 1024 + t * 4;
    int v0 = base     < n ? deg[base]     : 0;
    int v1 = base + 1 < n ? deg[base + 1] : 0;
    int v2 = base + 2 < n ? deg[base + 2] : 0;
    int v3 = base + 3 < n ? deg[base + 3] : 0;
    int s = v0 + v1 + v2 + v3;
    int sc = s;
    #pragma unroll
    for (int o = 1; o < 64; o <<= 1) { int xx = __shfl_up(sc, o); if (lane >= o) sc += xx; }
    if (lane == 63) wsum[w] = sc;
    __syncthreads();
    int wo = 0;
    #pragma unroll
    for (int k = 0; k < 4; ++k) if (k < w) wo += wsum[k];
    int p = wo + sc - s;
    if (base     < n) pre[base]     = p; p += v0;
    if (base + 1 < n) pre[base + 1] = p; p += v1;
    if (base + 2 < n) pre[base + 2] = p; p += v2;
    if (base + 3 < n) pre[base + 3] = p;
    if (t == 255) bsum[blockIdx.x] = wo + sc;
}
__global__ void scan2_kernel(int* __restrict__ bsum, int nb) {
    int lane = threadIdx.x;
    int v = lane < nb ? bsum[lane] : 0;
    int sc = v;
    #pragma unroll
    for (int o = 1; o < 64; o <<= 1) { int xx = __shfl_up(sc, o); if (lane >= o) sc += xx; }
    if (lane < nb) bsum[lane] = sc - v;
}
__global__ void scan3_csr_kernel(const int* __restrict__ pre, const int* __restrict__ bsum,
                                 int* __restrict__ offsets, int* __restrict__ cursor,
                                 int* __restrict__ csr, int n, int total) {
    int i = blockIdx.x * 256 + threadIdx.x;
    if (i < n) {
        int off = pre[i] + bsum[i >> 10];
        offsets[i] = off;
        cursor[i] = off + 1;
        csr[off] = i;                                  // self-loop slot 0
    }
    if (i == 0) offsets[n] = total;
}
__global__ void scatter_kernel(const int* __restrict__ src, const int* __restrict__ dst,
                               int* __restrict__ cursor, int* __restrict__ csr, int E) {
    int i = blockIdx.x * blockDim.x + threadIdx.x;
    if (i < E) {
        int pos = atomicAdd(&cursor[dst[i]], 1);
        csr[pos] = src[i];
    }
}

// ---------------------------------------------------------------------------
// Aggregation: single edge pass, post-normalized softmax, fp8 gather.
// Wave-uniform node index scalarized via readfirstlane -> csr & bounds become
// scalar loads, gather base addresses SALU; packed f32x2 accumulation.
// ---------------------------------------------------------------------------
__global__ void aggregate_kernel(const unsigned char* __restrict__ Hq,
                                 const float* __restrict__ alpha_src,
                                 const float* __restrict__ alpha_dst,
                                 const int* __restrict__ offsets,
                                 const int* __restrict__ csr,
                                 const float* __restrict__ b1, const float* __restrict__ b2,
                                 unsigned short* __restrict__ xcb, int N) {
    int n = __builtin_amdgcn_readfirstlane((int)((blockIdx.x * blockDim.x + threadIdx.x) >> 6));
    int lane = threadIdx.x & 63;
    if (n >= N) return;
    int beg = offsets[n], end = offsets[n + 1];
    int c0 = lane * 8;
    int hid = (lane < 32) ? (lane >> 3) : (4 + ((lane - 32) >> 2));
    float adh = alpha_dst[(size_t)n * AP + hid];

    float ssum = 0.f;
    f32x2 A0 = {0.f, 0.f}, A1 = {0.f, 0.f}, A2 = {0.f, 0.f}, A3 = {0.f, 0.f};

    int i = beg;
    for (; i + 4 <= end; i += 4) {
        int ss[4];
        #pragma unroll
        for (int u = 0; u < 4; ++u) ss[u] = csr[i + u];          // scalar loads (uniform addr)
        float lw[4];
        #pragma unroll
        for (int u = 0; u < 4; ++u) lw[u] = alpha_src[(size_t)ss[u] * AP + hid];
        uint2 hv[4];
        #pragma unroll
        for (int u = 0; u < 4; ++u) hv[u] = *(const uint2*)(Hq + (size_t)ss[u] * CC + c0);
        #pragma unroll
        for (int u = 0; u < 4; ++u) {
            float l = lw[u] + adh;
            l = fmaxf(l, 0.2f * l);                              // leaky relu
            float wv = __expf(l);
            ssum += wv;
            f32x2 wv2; wv2[0] = wv; wv2[1] = wv;
            A0 += __builtin_amdgcn_cvt_pk_f32_fp8(hv[u].x, false) * wv2;
            A1 += __builtin_amdgcn_cvt_pk_f32_fp8(hv[u].x, true)  * wv2;
            A2 += __builtin_amdgcn_cvt_pk_f32_fp8(hv[u].y, false) * wv2;
            A3 += __builtin_amdgcn_cvt_pk_f32_fp8(hv[u].y, true)  * wv2;
        }
    }
    for (; i < end; ++i) {
        int s0 = csr[i];
        float l = alpha_src[(size_t)s0 * AP + hid] + adh;
        uint2 hv0 = *(const uint2*)(Hq + (size_t)s0 * CC + c0);
        l = fmaxf(l, 0.2f * l);
        float wv = __expf(l);
        ssum += wv;
        f32x2 wv2; wv2[0] = wv; wv2[1] = wv;
        A0 += __builtin_amdgcn_cvt_pk_f32_fp8(hv0.x, false) * wv2;
        A1 += __builtin_amdgcn_cvt_pk_f32_fp8(hv0.x, true)  * wv2;
        A2 += __builtin_amdgcn_cvt_pk_f32_fp8(hv0.y, false) * wv2;
        A3 += __builtin_amdgcn_cvt_pk_f32_fp8(hv0.y, true)  * wv2;
    }

    float inv = 1.0f / (ssum + 1e-16f);
    const float* bb = (c0 < 256) ? (b1 + c0) : (b2 + (c0 - 256));
    float4 bb0 = *(const float4*)(bb), bb1 = *(const float4*)(bb + 4);
    float o[8];
    o[0] = A0[0] * inv + bb0.x; o[1] = A0[1] * inv + bb0.y;
    o[2] = A1[0] * inv + bb0.z; o[3] = A1[1] * inv + bb0.w;
    o[4] = A2[0] * inv + bb1.x; o[5] = A2[1] * inv + bb1.y;
    o[6] = A3[0] * inv + bb1.z; o[7] = A3[1] * inv + bb1.w;
    #pragma unroll
    for (int j = 0; j < 8; ++j) o[j] = o[j] > 0.f ? o[j] : expm1f(o[j]);
    unsigned short u[8];
    #pragma unroll
    for (int j = 0; j < 8; ++j) u[j] = f2bf(o[j]);
    i32x4 pk;
    pk[0] = (int)((unsigned)u[0] | ((unsigned)u[1] << 16));
    pk[1] = (int)((unsigned)u[2] | ((unsigned)u[3] << 16));
    pk[2] = (int)((unsigned)u[4] | ((unsigned)u[5] << 16));
    pk[3] = (int)((unsigned)u[6] | ((unsigned)u[7] << 16));
    __builtin_nontemporal_store(pk, (i32x4*)(xcb + (size_t)n * CC + c0));
}

// ---------------------------------------------------------------------------
// Launch
// ---------------------------------------------------------------------------
extern "C" void kernel_launch(void* const* d_in, const int* in_sizes, int n_in,
                              void* d_out, int out_size, void* d_ws, size_t ws_size,
                              hipStream_t stream) {
    const float* x     = (const float*)d_in[0];
    const int*   ei    = (const int*)d_in[1];
    const float* gamma = (const float*)d_in[2];
    const float* beta  = (const float*)d_in[3];
    const float* W1    = (const float*)d_in[4];
    const float* as1   = (const float*)d_in[5];
    const float* ad1   = (const float*)d_in[6];
    const float* b1    = (const float*)d_in[7];
    const float* W2    = (const float*)d_in[8];
    const float* as2   = (const float*)d_in[9];
    const float* ad2   = (const float*)d_in[10];
    const float* b2    = (const float*)d_in[11];
    const float* Wu    = (const float*)d_in[12];
    const float* bu    = (const float*)d_in[13];
    float* out = (float*)d_out;

    const int N = in_sizes[0] / CH;
    const int E = in_sizes[1] / 2;
    const int* src = ei;
    const int* dst = ei + E;

    char* w = (char*)d_ws;
    auto alloc = [&](size_t bytes) { char* p = w; w += (bytes + 255) & ~(size_t)255; return p; };
    unsigned char*  Hq  = (unsigned char*)alloc((size_t)N * CC);
    unsigned short* xnb = (unsigned short*)alloc((size_t)N * CH * 2);
    unsigned short* xcb = (unsigned short*)alloc((size_t)N * CC * 2);
    unsigned short* WT1 = (unsigned short*)alloc(512 * 256 * 2);
    unsigned short* WTu = (unsigned short*)alloc(256 * 512 * 2);
    float* alpha_src = (float*)alloc((size_t)N * AP * 4);
    float* alpha_dst = (float*)alloc((size_t)N * AP * 4);
    int* deg     = (int*)alloc((size_t)N * 4);
    int* pre     = (int*)alloc((size_t)N * 4);
    int* bsum    = (int*)alloc(64 * 4);
    int* offsets = (int*)alloc(((size_t)N + 1) * 4);
    int* cursor  = (int*)alloc((size_t)N * 4);
    int* csr     = (int*)alloc(((size_t)E + N) * 4);

    const int LNB = (N + 3) / 4;
    const int DEGB = (N + 255) / 256;
    fused_pre_kernel<<<LNB + 1024 + DEGB, 256, 0, stream>>>(x, gamma, beta, W1, W2, Wu,
                                                            xnb, WT1, WTu, deg, N, LNB);

    const int MB = (N + 127) / 128;
    const int MB8 = ((MB + 7) / 8) * 8;
    const int G1B = MB8 * 4;
    const int HB = (E + 255) / 256;
    gemm1_mfma<<<G1B + HB, 256, 0, stream>>>(xnb, WT1, as1, ad1, as2, ad2,
                                             Hq, alpha_src, alpha_dst, N, MB,
                                             dst, deg, E, G1B);

    int nb = (N + 1023) / 1024;
    scan1_kernel<<<nb, 256, 0, stream>>>(deg, pre, bsum, N);
    scan2_kernel<<<1, 64, 0, stream>>>(bsum, nb);
    scan3_csr_kernel<<<(N + 255) / 256, 256, 0, stream>>>(pre, bsum, offsets, cursor, csr, N, E + N);
    scatter_kernel<<<(E + 255) / 256, 256, 0, stream>>>(src, dst, cursor, csr, E);

    aggregate_kernel<<<(N + 3) / 4, 256, 0, stream>>>(Hq, alpha_src, alpha_dst, offsets, csr,
                                                      b1, b2, xcb, N);

    gemm2_mfma<<<MB8 * 2, 256, 0, stream>>>(xcb, WTu, bu, x, out, N, MB);
}